// Round 5
// baseline (262.115 us; speedup 1.0000x reference)
//
#include <hip/hip_runtime.h>

// EfficientAttention: N=8, C=256, H=W=128 (L=16384), HEADS=8, hc=32
// out = x + att,  att[n,h,cv,l] = sum_ck (ctx[ck,cv]/S[ck]) * softmax_ck(q)[ck,l]
// ctx[ck,cv] = sum_l exp(k[ck,l]) * v[cv,l],  S[ck] = sum_l exp(k[ck,l])

typedef __attribute__((ext_vector_type(8))) short short8;
typedef __attribute__((ext_vector_type(4))) float f32x4;

#define NB     8
#define CCH    256
#define LSP    16384
#define NHEADS 8
#define HC     32
#define NT     8      // 32-px tiles per block -> 256 px/block
#define NBUF   3      // staging depth 2 (triple buffer)

__device__ __forceinline__ unsigned short f2bf(float f) {
  union { float f; unsigned u; } v; v.f = f;
  unsigned r = v.u + 0x7fffu + ((v.u >> 16) & 1u);   // RNE
  return (unsigned short)(r >> 16);
}
__device__ __forceinline__ unsigned cvt_pk_bf16(float lo, float hi) {
  unsigned r;
  asm("v_cvt_pk_bf16_f32 %0, %1, %2" : "=v"(r) : "v"(lo), "v"(hi));
  return r;   // low 16 = bf16(lo), high 16 = bf16(hi)
}
__device__ __forceinline__ void gload_lds16(const unsigned short* g, unsigned short* l) {
  __builtin_amdgcn_global_load_lds(
      (const __attribute__((address_space(1))) unsigned int*)g,
      (__attribute__((address_space(3))) unsigned int*)l, 16, 0, 0);
}

// ---------------- kernel 0: weights -> bf16 head-grouped [k;v;q], zero ctx/S ----------------
__global__ void k_prep(const float* __restrict__ Wk, const float* __restrict__ bk,
                       const float* __restrict__ Wq, const float* __restrict__ bq,
                       const float* __restrict__ Wv, const float* __restrict__ bv,
                       unsigned short* __restrict__ Wb, float* __restrict__ bb,
                       float* __restrict__ ctx, float* __restrict__ S) {
  int idx = blockIdx.x * 256 + threadIdx.x;
  if (idx < NHEADS * 96 * CCH) {
    int c = idx & (CCH - 1);
    int row = (idx >> 8) % 96;
    int h = idx / (96 * CCH);
    int ch = h * HC;
    float val;
    if (row < HC)          val = Wk[(ch + row) * CCH + c];
    else if (row < 2 * HC) val = Wv[(ch + row - HC) * CCH + c];
    else                   val = Wq[(ch + row - 2 * HC) * CCH + c];
    Wb[idx] = f2bf(val);
  }
  if (idx < NHEADS * 96) {
    int row = idx % 96, h = idx / 96, ch = h * HC;
    float val;
    if (row < HC)          val = bk[ch + row];
    else if (row < 2 * HC) val = bv[ch + row - HC];
    else                   val = bq[ch + row - 2 * HC];
    bb[idx] = val;
  }
  if (idx < NB * NHEADS * HC * HC) ctx[idx] = 0.f;
  if (idx < NB * NHEADS * HC)      S[idx]   = 0.f;
}

// ---------------- kernel 0b: x [n][c][l] f32 -> xT [n][l][c] bf16 ----------------
__global__ __launch_bounds__(256)
void k_transpose(const float* __restrict__ x, unsigned short* __restrict__ xT) {
  __shared__ float tile[64][65];
  int b = blockIdx.x;
  int ct = b & 3;
  int lt = (b >> 2) & 255;
  int n  = b >> 10;
  int c0 = ct * 64, l0 = lt * 64;
  int t = threadIdx.x;
  int li = t & 63, cr = t >> 6;
  const float* xp = x + (size_t)n * CCH * LSP;
#pragma unroll
  for (int i = 0; i < 16; ++i) {
    int ci = cr * 16 + i;
    tile[ci][li] = xp[(size_t)(c0 + ci) * LSP + l0 + li];
  }
  __syncthreads();
  int cp = t & 31, l8 = t >> 5;    // c-pair, l-octet
  unsigned short* xo = xT + ((size_t)n * LSP + l0) * CCH + c0;
#pragma unroll
  for (int i = 0; i < 8; ++i) {
    int l = l8 * 8 + i;
    unsigned pk = (unsigned)f2bf(tile[2 * cp][l]) | ((unsigned)f2bf(tile[2 * cp + 1][l]) << 16);
    *(unsigned*)&xo[(size_t)l * CCH + 2 * cp] = pk;
  }
}

// ---------------- kernel 1: fused QKV, one block type, 12 waves ----------------
// grid 512 = 8n x 64 lgrp (256 px each); block 768 thr.
// waves 0-7: head w's k+v (64 rows in regs), swapped MFMA (lane = 4 contig px),
//   exp -> wave-private LDS strips -> ctx MFMA accumulate in regs, atomics once.
// waves 8-11: q of heads (w-8)*2,(w-8)*2+1 (64 rows), normal MFMA, in-reg softmax,
//   softmaxed bf16 q stored [l][ck] direct to global (no vm waits at all).
// x-tile staged by KV waves via global_load_lds, triple-buffered, vmcnt(2) counted.
__global__ __launch_bounds__(768, 3)
void k_fused(const unsigned short* __restrict__ xT,
             const unsigned short* __restrict__ Wb, const float* __restrict__ bb,
             unsigned short* __restrict__ qbuf, float* __restrict__ ctx,
             float* __restrict__ S) {
  __shared__ unsigned short xt[NBUF][32 * 256];     // 48 KiB
  __shared__ unsigned short ekv[8][2][32][40];      // 40 KiB strips (pitch 40)

  int bid = (int)blockIdx.x;
  int n = bid >> 6, lgrp = bid & 63;
  int l0 = lgrp << 8;
  int tid = threadIdx.x;
  int wid = tid >> 6, lane = tid & 63;
  int r16 = lane & 15, kg = lane >> 4;

  const unsigned short* xTn = xT + ((size_t)n << 14) * CCH;

  // stage 32px x 256ch tile: 16 x 1KB pieces, 2 per KV wave; dest linear,
  // source chunk-XOR-swizzled (both-sides involution, rule 21)
  auto stage = [&](int buf, int tt) {
    int lb = l0 + tt * 32;
#pragma unroll
    for (int i = 0; i < 2; ++i) {
      int f = wid * 2 + i;                 // 0..15
      int px = f * 2 + (lane >> 5);
      int c  = lane & 31;
      gload_lds16(xTn + ((size_t)(lb + px) << 8) + ((c ^ (px & 7)) << 3),
                  &xt[buf][f * 512]);
    }
  };

  if (wid < 8) { stage(0, 0); stage(1, 1); }

  if (wid < 8) {
    // ================= KV waves =================
    int h = wid;
    short8 af[4][8];     // rows rf*16+r16 of [k(32); v(32)]
#pragma unroll
    for (int rf = 0; rf < 4; ++rf)
#pragma unroll
      for (int kk = 0; kk < 8; ++kk)
        af[rf][kk] = *(const short8*)&Wb[(size_t)(h * 96 + rf * 16 + r16) * CCH + kk * 32 + kg * 8];
    float bias[4];
#pragma unroll
    for (int rf = 0; rf < 4; ++rf) bias[rf] = bb[h * 96 + rf * 16 + r16];

    f32x4 acc_ctx[2][2];
#pragma unroll
    for (int a = 0; a < 2; ++a)
#pragma unroll
      for (int b = 0; b < 2; ++b) acc_ctx[a][b] = (f32x4){0.f, 0.f, 0.f, 0.f};
    float sk0 = 0.f, sk1 = 0.f;

    __syncthreads();
    int cur = 0;
    for (int t = 0; t < NT; ++t) {
      if (t + 2 < NT) {
        int b2 = cur + 2; if (b2 >= NBUF) b2 -= NBUF;
        stage(b2, t + 2);
      }
      f32x4 acc[2][4];   // [pxf][rf]
#pragma unroll
      for (int a = 0; a < 2; ++a)
#pragma unroll
        for (int b = 0; b < 4; ++b) acc[a][b] = (f32x4){0.f, 0.f, 0.f, 0.f};
      const unsigned short* xb = &xt[cur][0];
#pragma unroll
      for (int kk = 0; kk < 8; ++kk) {
        int cw = (((kk * 4 + kg) ^ (r16 & 7)) << 3);
        short8 x0 = *(const short8*)&xb[r16 * 256 + cw];
        short8 x1 = *(const short8*)&xb[(16 + r16) * 256 + cw];
#pragma unroll
        for (int rf = 0; rf < 4; ++rf) {
          acc[0][rf] = __builtin_amdgcn_mfma_f32_16x16x32_bf16(x0, af[rf][kk], acc[0][rf], 0, 0, 0);
          acc[1][rf] = __builtin_amdgcn_mfma_f32_16x16x32_bf16(x1, af[rf][kk], acc[1][rf], 0, 0, 0);
        }
      }
      // scatter: lane holds (W-row = rf*16+r16, px = pxf*16+kg*4+r) -> b64 strips
#pragma unroll
      for (int pxf = 0; pxf < 2; ++pxf) {
#pragma unroll
        for (int rf = 0; rf < 4; ++rf) {
          float v0 = acc[pxf][rf][0] + bias[rf];
          float v1 = acc[pxf][rf][1] + bias[rf];
          float v2 = acc[pxf][rf][2] + bias[rf];
          float v3 = acc[pxf][rf][3] + bias[rf];
          if (rf < 2) {
            float e0 = __expf(v0), e1 = __expf(v1), e2 = __expf(v2), e3 = __expf(v3);
            if (rf == 0) sk0 += e0 + e1 + e2 + e3; else sk1 += e0 + e1 + e2 + e3;
            uint2 u = {cvt_pk_bf16(e0, e1), cvt_pk_bf16(e2, e3)};
            *(uint2*)&ekv[wid][0][rf * 16 + r16][pxf * 16 + kg * 4] = u;
          } else {
            uint2 u = {cvt_pk_bf16(v0, v1), cvt_pk_bf16(v2, v3)};
            *(uint2*)&ekv[wid][1][(rf - 2) * 16 + r16][pxf * 16 + kg * 4] = u;
          }
        }
      }
      // ctx += ek . v^T : wave-private strips, no cross-wave hazard
#pragma unroll
      for (int ckf = 0; ckf < 2; ++ckf)
#pragma unroll
        for (int cvf = 0; cvf < 2; ++cvf) {
          short8 a = *(const short8*)&ekv[wid][0][ckf * 16 + r16][kg * 8];
          short8 b = *(const short8*)&ekv[wid][1][cvf * 16 + r16][kg * 8];
          acc_ctx[ckf][cvf] = __builtin_amdgcn_mfma_f32_16x16x32_bf16(a, b, acc_ctx[ckf][cvf], 0, 0, 0);
        }
      __builtin_amdgcn_sched_barrier(0);
      if (t < NT - 2) { asm volatile("s_waitcnt vmcnt(2)" ::: "memory"); }
      else            { asm volatile("s_waitcnt vmcnt(0)" ::: "memory"); }
      __builtin_amdgcn_sched_barrier(0);
      __builtin_amdgcn_s_barrier();
      __builtin_amdgcn_sched_barrier(0);
      cur = (cur == NBUF - 1) ? 0 : cur + 1;
    }
    // flush once per block
    float* cp = ctx + ((size_t)(n * NHEADS + h) << 10);
#pragma unroll
    for (int ckf = 0; ckf < 2; ++ckf)
#pragma unroll
      for (int cvf = 0; cvf < 2; ++cvf)
#pragma unroll
        for (int rr = 0; rr < 4; ++rr)
          atomicAdd(&cp[(ckf * 16 + kg * 4 + rr) * HC + cvf * 16 + r16], acc_ctx[ckf][cvf][rr]);
#pragma unroll
    for (int rf = 0; rf < 2; ++rf) {
      float s = (rf == 0) ? sk0 : sk1;
      s += __shfl_xor(s, 16);
      s += __shfl_xor(s, 32);
      if (kg == 0) atomicAdd(&S[(n * NHEADS + h) * HC + rf * 16 + r16], s);
    }
  } else {
    // ================= Q waves =================
    int wq = wid - 8;
    short8 af[4][8];     // q rows of heads 2*wq, 2*wq+1
#pragma unroll
    for (int rf = 0; rf < 4; ++rf) {
      int hq = wq * 2 + (rf >> 1);
#pragma unroll
      for (int kk = 0; kk < 8; ++kk)
        af[rf][kk] = *(const short8*)&Wb[(size_t)(hq * 96 + 64 + (rf & 1) * 16 + r16) * CCH + kk * 32 + kg * 8];
    }
    float bias[4][4];
#pragma unroll
    for (int rf = 0; rf < 4; ++rf) {
      int hq = wq * 2 + (rf >> 1);
#pragma unroll
      for (int rr = 0; rr < 4; ++rr)
        bias[rf][rr] = bb[hq * 96 + 64 + (rf & 1) * 16 + kg * 4 + rr];
    }

    __syncthreads();
    int cur = 0;
    for (int t = 0; t < NT; ++t) {
      int lb = l0 + t * 32;
      f32x4 acc[4][2];   // [rf][pxf]
#pragma unroll
      for (int a = 0; a < 4; ++a)
#pragma unroll
        for (int b = 0; b < 2; ++b) acc[a][b] = (f32x4){0.f, 0.f, 0.f, 0.f};
      const unsigned short* xb = &xt[cur][0];
#pragma unroll
      for (int kk = 0; kk < 8; ++kk) {
        int cw = (((kk * 4 + kg) ^ (r16 & 7)) << 3);
        short8 x0 = *(const short8*)&xb[r16 * 256 + cw];
        short8 x1 = *(const short8*)&xb[(16 + r16) * 256 + cw];
#pragma unroll
        for (int rf = 0; rf < 4; ++rf) {
          acc[rf][0] = __builtin_amdgcn_mfma_f32_16x16x32_bf16(af[rf][kk], x0, acc[rf][0], 0, 0, 0);
          acc[rf][1] = __builtin_amdgcn_mfma_f32_16x16x32_bf16(af[rf][kk], x1, acc[rf][1], 0, 0, 0);
        }
      }
      // softmax over ck (q logits bounded ~±2.6 -> no max-subtraction) + b64 stores
#pragma unroll
      for (int hb = 0; hb < 2; ++hb) {
        int hq = wq * 2 + hb;
        unsigned short* qb = qbuf + (((size_t)(n * NHEADS + hq) * LSP + lb) << 5);
#pragma unroll
        for (int pxf = 0; pxf < 2; ++pxf) {
          float vl[4], vh[4];
          float s = 0.f;
#pragma unroll
          for (int rr = 0; rr < 4; ++rr) {
            vl[rr] = __expf(acc[hb * 2][pxf][rr] + bias[hb * 2][rr]);
            vh[rr] = __expf(acc[hb * 2 + 1][pxf][rr] + bias[hb * 2 + 1][rr]);
            s += vl[rr] + vh[rr];
          }
          s += __shfl_xor(s, 16);
          s += __shfl_xor(s, 32);
          float inv = 1.f / s;
          uint2 ul = {cvt_pk_bf16(vl[0] * inv, vl[1] * inv), cvt_pk_bf16(vl[2] * inv, vl[3] * inv)};
          uint2 uh = {cvt_pk_bf16(vh[0] * inv, vh[1] * inv), cvt_pk_bf16(vh[2] * inv, vh[3] * inv)};
          size_t po = ((size_t)(pxf * 16 + r16) << 5) + kg * 4;
          *(uint2*)&qb[po] = ul;
          *(uint2*)&qb[po + 16] = uh;
        }
      }
      __builtin_amdgcn_s_barrier();    // no vm wait: stores retire on their own
      cur = (cur == NBUF - 1) ? 0 : cur + 1;
    }
  }
}

// ---------------- kernel 2: ctx/S, transpose, -> bf16 ----------------
__global__ void k_norm(const float* __restrict__ ctx, const float* __restrict__ S,
                       unsigned short* __restrict__ ctxT) {
  int idx = blockIdx.x * 256 + threadIdx.x;  // 65536 = [n][h][ck][cv]
  int cv = idx & 31, ck = (idx >> 5) & 31, nh = idx >> 10;
  float v = ctx[idx] / S[(nh << 5) + ck];
  ctxT[(nh << 10) + (cv << 5) + ck] = f2bf(v);
}

// ---------------- kernel 3: att = ctxT (32x32) x q_soft (32 x L) + residual ----------------
__global__ __launch_bounds__(256)
void k_att(const float* __restrict__ x, const unsigned short* __restrict__ qbuf,
           const unsigned short* __restrict__ ctxT, float* __restrict__ out) {
  int b = blockIdx.x;
  int lc = b & 63;
  int nh = b >> 6;
  int h = nh & 7, n = nh >> 3;
  int tid = threadIdx.x, wid = tid >> 6, lane = tid & 63;
  int r16 = lane & 15, kg = lane >> 4;
  int lw = lc * 256 + wid * 64;

  const unsigned short* cp = ctxT + ((size_t)nh << 10);
  short8 a0 = *(const short8*)&cp[(r16 << 5) + kg * 8];          // A[cv][ck], cv 0-15
  short8 a1 = *(const short8*)&cp[((16 + r16) << 5) + kg * 8];   // cv 16-31
  const unsigned short* qb = qbuf + (((size_t)nh * LSP) << 5);
  const float* xp = x   + ((size_t)n * CCH + (size_t)h * HC) * LSP;
  float*       op = out + ((size_t)n * CCH + (size_t)h * HC) * LSP;

#pragma unroll
  for (int t = 0; t < 4; ++t) {
    int l = lw + t * 16;
    short8 bf = *(const short8*)&qb[((size_t)(l + r16) << 5) + kg * 8];  // softmaxed q [l][ck]
    f32x4 d0 = {0, 0, 0, 0}, d1 = {0, 0, 0, 0};
    d0 = __builtin_amdgcn_mfma_f32_16x16x32_bf16(a0, bf, d0, 0, 0, 0);
    d1 = __builtin_amdgcn_mfma_f32_16x16x32_bf16(a1, bf, d1, 0, 0, 0);
#pragma unroll
    for (int r = 0; r < 4; ++r) {
      int cv = kg * 4 + r;
      int li = l + r16;
      op[(size_t)cv * LSP + li]        = d0[r] + xp[(size_t)cv * LSP + li];
      op[(size_t)(cv + 16) * LSP + li] = d1[r] + xp[(size_t)(cv + 16) * LSP + li];
    }
  }
}

extern "C" void kernel_launch(void* const* d_in, const int* in_sizes, int n_in,
                              void* d_out, int out_size, void* d_ws, size_t ws_size,
                              hipStream_t stream) {
  (void)in_sizes; (void)n_in; (void)out_size; (void)ws_size;
  const float* x  = (const float*)d_in[0];
  const float* Wk = (const float*)d_in[1];
  const float* bk = (const float*)d_in[2];
  const float* Wq = (const float*)d_in[3];
  const float* bq = (const float*)d_in[4];
  const float* Wv = (const float*)d_in[5];
  const float* bv = (const float*)d_in[6];
  float* out = (float*)d_out;

  char* ws = (char*)d_ws;
  unsigned short* Wb   = (unsigned short*)(ws + 0);          //   393216
  float*          bbp  = (float*)(ws + 393216);              //     3072
  float*          ctx  = (float*)(ws + 396288);              //   262144
  unsigned short* ctxT = (unsigned short*)(ws + 658432);     //   131072
  float*          S    = (float*)(ws + 789504);              //     8192
  unsigned short* qbuf = (unsigned short*)(ws + 797696);     // 67108864
  unsigned short* xT   = (unsigned short*)(ws + 67906560);   // 67108864 -> 135015424 total

  k_prep<<<768, 256, 0, stream>>>(Wk, bk, Wq, bq, Wv, bv, Wb, bbp, ctx, S);
  k_transpose<<<NB * 256 * 4, 256, 0, stream>>>(x, xT);
  k_fused<<<512, 768, 0, stream>>>(xT, Wb, bbp, qbuf, ctx, S);
  k_norm<<<256, 256, 0, stream>>>(ctx, S, ctxT);
  k_att<<<NB * NHEADS * 64, 256, 0, stream>>>(x, qbuf, ctxT, out);
}